// Round 2
// baseline (184.929 us; speedup 1.0000x reference)
//
#include <hip/hip_runtime.h>
#include <math.h>

// Problem constants
#define Bn    64
#define Cn    3
#define IMG   224
#define PLANE (IMG*IMG)      // 50176
#define C1    6
#define P1    110            // conv1(220) + maxpool2 -> 110
#define P2    106            // conv2 output spatial
#define NVALID (P2*P2)       // 11236
#define Hh    32
#define Ww    64
#define UPR   10
#define UPT   10
#define Hg    (Hh*UPR)       // 320
#define Wg    (Ww*UPT)       // 640
#define POOLED_SIZE (Bn*Cn*Hh*Ww)   // 393216
#define NCHUNK 28            // 28 chunks x 4 pooled rows = 112 >= 110
#define PSTRIDE 152          // padded 150-float partial slot
#define ROWB  (IMG*8)        // 1792 B: one NHWC4-f16 input row
#define TPB1  448            // 7 waves: 14 strips / 7 = 2 each, perfect balance

typedef unsigned short u16;
typedef unsigned long long ull;
typedef _Float16 h8v __attribute__((ext_vector_type(8)));   // 8 f16 (4 VGPR) MFMA frag
typedef float f4v __attribute__((ext_vector_type(4)));      // 16x16 MFMA accumulator

// workspace: partials (B*28*152 f32) | pad (B*2 f32) | x4h (B*224*224*4 f16)
#define PART_FLOATS ((size_t)Bn * NCHUNK * PSTRIDE)     // 272,384
#define X4B_U16     ((size_t)Bn * PLANE * 4)
#define WS_NEEDED   ((PART_FLOATS + Bn * 2) * 4 + X4B_U16 * 2)

__device__ __forceinline__ unsigned hpack(float a, float b) {
    union { _Float16 h; u16 u; } x, y;
    x.h = (_Float16)a; y.h = (_Float16)b;
    return (unsigned)x.u | ((unsigned)y.u << 16);
}
__device__ __forceinline__ float h2lo(unsigned v) {
    union { _Float16 h; u16 u; } c; c.u = (u16)(v & 0xffffu); return (float)c.h;
}
__device__ __forceinline__ float h2hi(unsigned v) {
    union { _Float16 h; u16 u; } c; c.u = (u16)(v >> 16); return (float)c.h;
}

// group-local broadcast: read lane (group_base + idx) of a 16-lane group
#define GSHFL(v, idx) __shfl((v), (lane & 48) + (idx), 64)

// -------------------------------------------------------------------------
// K1 (MFMA, single f16 pass): fused conv1 (implicit GEMM on matrix cores;
// f16 inputs+weights: input rounding 2^-11 vs round-1's bf16 2^-8, so one
// pass replaces the bf16 hi+lo pair at BETTER precision) + maxpool2 +
// f16-NHWC4 pack + windowed row sums -> per-chunk partials.
//
// Block = 448 thr (7 waves x 2 strips = 14, no imbalance). Wave 0 builds
// the 5 A-frags into LDS once per block (kills the per-lane 40-gather +
// 80-cvt A-build that dominated round-1 overhead); waves 1-6 stage.
// K-map k = ic + 4*kx; C-layout col=lane&15, row=(lane>>4)*4+reg (verified).
// -------------------------------------------------------------------------
__global__ __launch_bounds__(TPB1) void k1_fused(
    const float* __restrict__ x,      // (B,3,224,224)
    const float* __restrict__ w1,     // (6,3,5,5)
    const float* __restrict__ b1,     // (6,)
    float* __restrict__ partial,      // (B,28,PSTRIDE)
    u16* __restrict__ x4h,            // (B,224,224,4) f16 out
    int do_pack)
{
    __shared__ __attribute__((aligned(16))) unsigned char xs[12 * ROWB + 128];
    __shared__ __attribute__((aligned(16))) _Float16 sa[5][64][8];  // A-frags
    __shared__ float rowR[7][C1][4];     // [wave][oc][py]  row-sum partials
    __shared__ float edgeLo[4][C1][4];   // [py][oc][j]  S_{j+1} = cols 0..j
    __shared__ float edgeHi[4][C1][4];   // [py][oc][j]  U_{j+1} = cols 109-j..109

    const int b     = blockIdx.y;
    const int chunk = blockIdx.x;
    const int tid   = threadIdx.x;
    const int wid   = tid >> 6;
    const int lane  = tid & 63;
    const int n     = lane & 15;      // B col / A row / C col
    const int g     = lane >> 4;      // K-group (and C row-group)
    const int gy0   = chunk * 8;      // first input row of this chunk

    const float* xb = x + (size_t)b * (Cn * PLANE);
    u16* ob = x4h + (size_t)b * PLANE * 4;

    if (wid == 0) {
        // ---- wave 0: build A-frags (weights, k = ic + 4*kx) into LDS ----
        #pragma unroll
        for (int ky = 0; ky < 5; ++ky) {
            #pragma unroll
            for (int j = 0; j < 8; ++j) {
                const int kmem = g * 8 + j;
                const int ic = kmem & 3, kx = kmem >> 2;
                float w = 0.0f;
                if (n < C1 && ic < 3 && kx < 5)
                    w = w1[((n * 3 + ic) * 5 + ky) * 5 + kx];
                sa[ky][lane][j] = (_Float16)w;
            }
        }
    } else {
        // ---- waves 1-6: stage fp32 NCHW -> f16 NHWC4 LDS (+ x4h pack) ----
        for (int i = tid - 64; i < 12 * 112; i += TPB1 - 64) {
            const int r = i / 112;              // staged row 0..11
            const int p = i - r * 112;          // pixel-pair 0..111
            const int gy = gy0 + r;
            uint4 U; U.x = U.y = U.z = U.w = 0u;
            if (gy < IMG) {
                const float2 v0 = *(const float2*)(xb + 0 * PLANE + gy * IMG + 2 * p);
                const float2 v1 = *(const float2*)(xb + 1 * PLANE + gy * IMG + 2 * p);
                const float2 v2 = *(const float2*)(xb + 2 * PLANE + gy * IMG + 2 * p);
                U.x = hpack(v0.x, v1.x);
                U.y = hpack(v2.x, 0.0f);
                U.z = hpack(v0.y, v1.y);
                U.w = hpack(v2.y, 0.0f);
            }
            *(uint4*)(xs + r * ROWB + p * 16) = U;
            if (do_pack && r < 8)               // rows gy0..gy0+7 owned
                *(uint4*)(ob + ((size_t)gy * IMG + 2 * p) * 4) = U;
        }
    }
    __syncthreads();

    // per-lane A-frags from LDS (one b128 each)
    h8v a[5];
    #pragma unroll
    for (int ky = 0; ky < 5; ++ky) a[ky] = *(const h8v*)&sa[ky][lane][0];
    f4v binit;
    #pragma unroll
    for (int e = 0; e < 4; ++e) {
        const int oc = g * 4 + e;
        binit[e] = (oc < C1) ? b1[oc] : 0.0f;
    }

    float colsum[4][4];
    #pragma unroll
    for (int py = 0; py < 4; ++py)
        #pragma unroll
        for (int e = 0; e < 4; ++e) colsum[py][e] = 0.0f;

    #pragma unroll
    for (int si = 0; si < 2; ++si) {
        const int s = wid * 2 + si;         // strip: conv cols s*16 .. s*16+15
        const unsigned sByte = (unsigned)(s * 128 + n * 8 + g * 16);

        f4v acc[8];
        #pragma unroll
        for (int q = 0; q < 8; ++q) acc[q] = binit;

        #pragma unroll
        for (int r = 0; r < 12; ++r) {
            h8v bf;
            const unsigned char* bp = xs + r * ROWB + sByte;
            ((ull*)&bf)[0] = *(const ull*)bp;
            ((ull*)&bf)[1] = *(const ull*)(bp + 8);
            #pragma unroll
            for (int ky = 0; ky < 5; ++ky) {
                const int q = r - ky;
                if (q >= 0 && q < 8)
                    acc[q] = __builtin_amdgcn_mfma_f32_16x16x32_f16(
                        a[ky], bf, acc[q], 0, 0, 0);
            }
        }

        // maxpool 2x2 + edge capture + col accumulation
        #pragma unroll
        for (int py = 0; py < 4; ++py) {
            #pragma unroll
            for (int e = 0; e < 4; ++e) {
                float t = fmaxf(acc[2 * py][e], acc[2 * py + 1][e]);
                t = fmaxf(t, __shfl_xor(t, 1, 64));   // pair lanes = pooled col
                if (s == 13 && n >= 12) t = 0.0f;     // junk cols 110,111
                colsum[py][e] += t;
                const int oc = g * 4 + e;
                if (s == 0) {                          // pooled cols 0..3
                    const float c0 = GSHFL(t, 0), c1 = GSHFL(t, 2);
                    const float c2 = GSHFL(t, 4), c3 = GSHFL(t, 6);
                    const float S1 = c0, S2 = S1 + c1, S3 = S2 + c2, S4 = S3 + c3;
                    const float sv = (n == 0) ? S1 : (n == 1) ? S2 : (n == 2) ? S3 : S4;
                    if (n < 4 && oc < C1) edgeLo[py][oc][n] = sv;
                }
                if (s == 13) {                         // pooled cols 106..109
                    const float d109 = GSHFL(t, 10), d108 = GSHFL(t, 8);
                    const float d107 = GSHFL(t, 6),  d106 = GSHFL(t, 4);
                    const float U1 = d109, U2 = U1 + d108, U3 = U2 + d107, U4 = U3 + d106;
                    const float uv = (n == 0) ? U1 : (n == 1) ? U2 : (n == 2) ? U3 : U4;
                    if (n < 4 && oc < C1) edgeHi[py][oc][n] = uv;
                }
            }
        }
    }

    // per-wave row sums: reduce 8 same-parity lanes (each pooled col once)
    #pragma unroll
    for (int py = 0; py < 4; ++py) {
        #pragma unroll
        for (int e = 0; e < 4; ++e) {
            float v = colsum[py][e];
            v += __shfl_xor(v, 2, 64);
            v += __shfl_xor(v, 4, 64);
            v += __shfl_xor(v, 8, 64);
            const int oc = g * 4 + e;
            if (n == 0 && oc < C1) rowR[wid][oc][py] = v;
        }
    }
    __syncthreads();

    // final: slot(oc,ky,kx) = sum_py valid(py,ky) * (rowsum - S_kx - U_{4-kx})
    if (tid < 150) {
        const int oc = tid / 25;
        const int rem = tid - oc * 25;
        const int ky = rem / 5, kx = rem - ky * 5;
        float total = 0.0f;
        #pragma unroll
        for (int py = 0; py < 4; ++py) {
            const int y = chunk * 4 + py;
            const bool valid = (y < P1) && ((unsigned)(y - ky) <= 105u);
            float v = rowR[0][oc][py] + rowR[1][oc][py] + rowR[2][oc][py]
                    + rowR[3][oc][py] + rowR[4][oc][py] + rowR[5][oc][py]
                    + rowR[6][oc][py];
            if (kx > 0) v -= edgeLo[py][oc][kx - 1];
            if (kx < 4) v -= edgeHi[py][oc][3 - kx];
            total += valid ? v : 0.0f;
        }
        partial[((size_t)b * NCHUNK + chunk) * PSTRIDE + tid] = total;
    }
}

// -------------------------------------------------------------------------
// Inline head (ex-K2), run redundantly per k3 block (L2-hot partials):
// wsum -> feat -> fc1+relu -> fc2+sigmoid*5 -> sWt + weight output.
// Removes one kernel launch + its gap from the critical path.
// -------------------------------------------------------------------------
#define K3_HEAD_BODY                                                          \
    if (tid < 150) {                                                          \
        const float* p = partial + (size_t)b * NCHUNK * PSTRIDE + tid;        \
        float s = 0.0f;                                                       \
        _Pragma("unroll")                                                     \
        for (int c = 0; c < NCHUNK; ++c) s += p[c * PSTRIDE];                 \
        wsb[tid] = s;                                                         \
    }                                                                         \
    __syncthreads();                                                          \
    if (tid < 16) {                                                           \
        float s = 0.0f;                                                       \
        for (int j = 0; j < 150; ++j) s += w2[tid * 150 + j] * wsb[j];        \
        sfeat[tid] = b2[tid] + s * (1.0f / (float)NVALID);                    \
    }                                                                         \
    __syncthreads();                                                          \
    if (tid < 8) {                                                            \
        float s = fc1b[tid];                                                  \
        _Pragma("unroll")                                                     \
        for (int j = 0; j < 16; ++j) s += fc1w[tid * 16 + j] * sfeat[j];      \
        sh[tid] = fmaxf(s, 0.0f);                                             \
    }                                                                         \
    __syncthreads();                                                          \
    if (tid < 2) {                                                            \
        float s = fc2b[tid];                                                  \
        _Pragma("unroll")                                                     \
        for (int j = 0; j < 8; ++j) s += fc2w[tid * 8 + j] * sh[j];           \
        float sig = (s >= 0.0f) ? (1.0f / (1.0f + expf(-s)))                  \
                                : (expf(s) / (1.0f + expf(s)));               \
        const float wgt = 5.0f * sig;                                         \
        sWt[tid] = wgt;                                                       \
        out[POOLED_SIZE + b * 2 + tid] = wgt;                                 \
    }                                                                         \
    __syncthreads();

// -------------------------------------------------------------------------
// Clamp-coordinate sampling (equivalent to corner-clamp border mode).
// -------------------------------------------------------------------------
__device__ __forceinline__ void sample_coords(
    float gxn, float gyn, int& x0, int& y0, float& wx, float& wy)
{
    float ix = ((gxn + 1.0f) * (float)IMG - 1.0f) * 0.5f;
    float iy = ((gyn + 1.0f) * (float)IMG - 1.0f) * 0.5f;
    ix = fminf(fmaxf(ix, 0.0f), (float)(IMG - 1));
    iy = fminf(fmaxf(iy, 0.0f), (float)(IMG - 1));
    x0 = (int)ix; if (x0 > IMG - 2) x0 = IMG - 2;
    y0 = (int)iy; if (y0 > IMG - 2) y0 = IMG - 2;
    wx = ix - (float)x0;
    wy = iy - (float)y0;
}

// -------------------------------------------------------------------------
// K3 (f16 NHWC4): inline head + log-polar grid sample + 10x10 avg pool.
// Gathers merged: px (x0,x0+1) are contiguous 16B in NHWC4 -> one uint4
// per row per tap (2 loads/tap instead of 4) — attacks TA throughput.
// XCD-affinity swizzle: b = (L&7) + 8*(q>>5), 8 images/XCD (3.2MB <= L2).
// -------------------------------------------------------------------------
__global__ __launch_bounds__(640) void k3_sample_pool_f16(
    const u16* __restrict__ x4h,      // (B,224,224,4) f16
    const float* __restrict__ ltp,
    const float* __restrict__ partial,
    const float* __restrict__ w2,  const float* __restrict__ b2,
    const float* __restrict__ fc1w, const float* __restrict__ fc1b,
    const float* __restrict__ fc2w, const float* __restrict__ fc2b,
    float* __restrict__ out)
{
    __shared__ float part[3 * Wg];
    __shared__ float wsb[150];
    __shared__ float sfeat[16];
    __shared__ float sh[8];
    __shared__ float sWt[2];

    const int L = blockIdx.x;         // 0..2047
    const int q = L >> 3;             // 0..255
    const int h = q & 31;
    const int b = (L & 7) + 8 * (q >> 5);
    const int tid = threadIdx.x;

    K3_HEAD_BODY

    const float w0 = sWt[0];
    const float w1 = sWt[1];
    const float l0 = ltp[b * 2 + 0];
    const float l1 = ltp[b * 2 + 1];
    const float start = logf(0.01f * w0);
    const float stop  = logf(0.6f  * w1);
    const float dr = stop - start;

    const float angle = 6.283185307179586f * (float)tid / (float)Wg;
    const float sn = __sinf(angle);
    const float cs = __cosf(angle);

    const u16* xb4 = x4h + (size_t)b * PLANE * 4;

    const float ratio = expf(dr * (1.0f / (float)(Hg - 1)));
    float r = expf(start + dr * ((float)(h * UPR) / (float)(Hg - 1)));

    float acc0 = 0.0f, acc1 = 0.0f, acc2 = 0.0f;
    #pragma unroll
    for (int i = 0; i < UPR; ++i) {
        int x0, y0; float wx, wy;
        sample_coords(r * sn + l0, r * cs + l1, x0, y0, wx, wy);
        r *= ratio;

        const u16* base = xb4 + ((size_t)(y0 * IMG + x0)) * 4;
        const uint4 R0 = *(const uint4*)(base);            // px x0 | x0+1, row y0
        const uint4 R1 = *(const uint4*)(base + IMG * 4);  // row y0+1

        const float wx0 = 1.0f - wx, wy0 = 1.0f - wy;
        const float w00 = wx0 * wy0, w01 = wx * wy0;
        const float w10 = wx0 * wy,  w11 = wx * wy;

        acc0 += w00*h2lo(R0.x) + w01*h2lo(R0.z) + w10*h2lo(R1.x) + w11*h2lo(R1.z);
        acc1 += w00*h2hi(R0.x) + w01*h2hi(R0.z) + w10*h2hi(R1.x) + w11*h2hi(R1.z);
        acc2 += w00*h2lo(R0.y) + w01*h2lo(R0.w) + w10*h2lo(R1.y) + w11*h2lo(R1.w);
    }
    part[0 * Wg + tid] = acc0;
    part[1 * Wg + tid] = acc1;
    part[2 * Wg + tid] = acc2;
    __syncthreads();

    if (tid < Cn * Ww) {
        const int c = tid / Ww;
        const int w = tid % Ww;
        const float* p = part + c * Wg + w * UPT;
        float s = 0.0f;
        #pragma unroll
        for (int j = 0; j < UPT; ++j) s += p[j];
        out[(((size_t)b * Cn + c) * Hh + h) * Ww + w] = s * (1.0f / (UPR * UPT));
    }
}

// -------------------------------------------------------------------------
// K3 fallback (NCHW fp32 scalar gathers) — only if ws too small for x4h.
// -------------------------------------------------------------------------
__global__ __launch_bounds__(640) void k3_sample_pool_nchw(
    const float* __restrict__ x, const float* __restrict__ ltp,
    const float* __restrict__ partial,
    const float* __restrict__ w2,  const float* __restrict__ b2,
    const float* __restrict__ fc1w, const float* __restrict__ fc1b,
    const float* __restrict__ fc2w, const float* __restrict__ fc2b,
    float* __restrict__ out)
{
    __shared__ float part[3 * Wg];
    __shared__ float wsb[150];
    __shared__ float sfeat[16];
    __shared__ float sh[8];
    __shared__ float sWt[2];

    const int L = blockIdx.x;
    const int q = L >> 3;
    const int h = q & 31;
    const int b = (L & 7) + 8 * (q >> 5);
    const int tid = threadIdx.x;

    K3_HEAD_BODY

    const float w0 = sWt[0];
    const float w1 = sWt[1];
    const float l0 = ltp[b * 2 + 0];
    const float l1 = ltp[b * 2 + 1];
    const float start = logf(0.01f * w0);
    const float stop  = logf(0.6f  * w1);
    const float dr = stop - start;
    const float angle = 6.283185307179586f * (float)tid / (float)Wg;
    const float sn = __sinf(angle);
    const float cs = __cosf(angle);
    const float* xb = x + (size_t)b * Cn * PLANE;

    const float ratio = expf(dr * (1.0f / (float)(Hg - 1)));
    float r = expf(start + dr * ((float)(h * UPR) / (float)(Hg - 1)));

    float acc0 = 0.0f, acc1 = 0.0f, acc2 = 0.0f;
    #pragma unroll
    for (int i = 0; i < UPR; ++i) {
        int x0, y0; float wx, wy;
        sample_coords(r * sn + l0, r * cs + l1, x0, y0, wx, wy);
        r *= ratio;
        const float wx0 = 1.0f - wx, wy0 = 1.0f - wy;
        const float w00 = wx0 * wy0, w01 = wx * wy0;
        const float w10 = wx0 * wy,  w11 = wx * wy;
        const int o00 = y0 * IMG + x0;
        acc0 += w00*xb[o00] + w01*xb[o00+1] + w10*xb[o00+IMG] + w11*xb[o00+IMG+1];
        const float* x1p = xb + PLANE;
        acc1 += w00*x1p[o00] + w01*x1p[o00+1] + w10*x1p[o00+IMG] + w11*x1p[o00+IMG+1];
        const float* x2p = xb + 2 * PLANE;
        acc2 += w00*x2p[o00] + w01*x2p[o00+1] + w10*x2p[o00+IMG] + w11*x2p[o00+IMG+1];
    }
    part[0 * Wg + tid] = acc0;
    part[1 * Wg + tid] = acc1;
    part[2 * Wg + tid] = acc2;
    __syncthreads();

    if (tid < Cn * Ww) {
        const int c = tid / Ww;
        const int w = tid % Ww;
        const float* p = part + c * Wg + w * UPT;
        float s = 0.0f;
        #pragma unroll
        for (int j = 0; j < UPT; ++j) s += p[j];
        out[(((size_t)b * Cn + c) * Hh + h) * Ww + w] = s * (1.0f / (UPR * UPT));
    }
}

// -------------------------------------------------------------------------
extern "C" void kernel_launch(void* const* d_in, const int* in_sizes, int n_in,
                              void* d_out, int out_size, void* d_ws, size_t ws_size,
                              hipStream_t stream) {
    const float* x       = (const float*)d_in[0];
    const float* ltp     = (const float*)d_in[1];
    const float* conv1_w = (const float*)d_in[2];
    const float* conv1_b = (const float*)d_in[3];
    const float* conv2_w = (const float*)d_in[4];
    const float* conv2_b = (const float*)d_in[5];
    const float* fc1_w   = (const float*)d_in[6];
    const float* fc1_b   = (const float*)d_in[7];
    const float* fc2_w   = (const float*)d_in[8];
    const float* fc2_b   = (const float*)d_in[9];
    float* out = (float*)d_out;

    const int do_pack = (ws_size >= WS_NEEDED) ? 1 : 0;

    float* part_ws = (float*)d_ws;                       // B*28*PSTRIDE
    u16*   x4h     = (u16*)(part_ws + PART_FLOATS + Bn * 2);  // 8B-aligned

    k1_fused<<<dim3(NCHUNK, Bn), dim3(TPB1), 0, stream>>>(
        x, conv1_w, conv1_b, part_ws, x4h, do_pack);
    if (do_pack)
        k3_sample_pool_f16<<<dim3(Hh * Bn), dim3(Wg), 0, stream>>>(
            x4h, ltp, part_ws, conv2_w, conv2_b,
            fc1_w, fc1_b, fc2_w, fc2_b, out);
    else
        k3_sample_pool_nchw<<<dim3(Hh * Bn), dim3(Wg), 0, stream>>>(
            x, ltp, part_ws, conv2_w, conv2_b,
            fc1_w, fc1_b, fc2_w, fc2_b, out);
}

// Round 3
// 179.046 us; speedup vs baseline: 1.0329x; 1.0329x over previous
//
#include <hip/hip_runtime.h>
#include <math.h>

// Problem constants
#define Bn    64
#define Cn    3
#define IMG   224
#define PLANE (IMG*IMG)      // 50176
#define C1    6
#define P1    110            // conv1(220) + maxpool2 -> 110
#define P2    106            // conv2 output spatial
#define NVALID (P2*P2)       // 11236
#define Hh    32
#define Ww    64
#define UPR   10
#define UPT   10
#define Hg    (Hh*UPR)       // 320
#define Wg    (Ww*UPT)       // 640
#define POOLED_SIZE (Bn*Cn*Hh*Ww)   // 393216
#define NCHUNK 28            // 28 chunks x 4 pooled rows = 112 >= 110
#define PSTRIDE 152          // padded 150-float partial slot
#define ROWB  (IMG*8)        // 1792 B: one NHWC4-f16 input row
#define TPB1  448            // 7 waves: 14 strips / 7 = 2 each, perfect balance

typedef unsigned short u16;
typedef unsigned long long ull;
typedef _Float16 h8v __attribute__((ext_vector_type(8)));   // 8 f16 (4 VGPR) MFMA frag
typedef float f4v __attribute__((ext_vector_type(4)));      // 16x16 MFMA accumulator

// workspace: partials (B*28*152 f32) | wt (B*2 f32) | x4h (B*224*224*4 f16)
#define PART_FLOATS ((size_t)Bn * NCHUNK * PSTRIDE)     // 272,384
#define X4B_U16     ((size_t)Bn * PLANE * 4)
#define WS_NEEDED   ((PART_FLOATS + Bn * 2) * 4 + X4B_U16 * 2)

__device__ __forceinline__ unsigned hpack(float a, float b) {
    union { _Float16 h; u16 u; } x, y;
    x.h = (_Float16)a; y.h = (_Float16)b;
    return (unsigned)x.u | ((unsigned)y.u << 16);
}
__device__ __forceinline__ float h2lo(unsigned v) {
    union { _Float16 h; u16 u; } c; c.u = (u16)(v & 0xffffu); return (float)c.h;
}
__device__ __forceinline__ float h2hi(unsigned v) {
    union { _Float16 h; u16 u; } c; c.u = (u16)(v >> 16); return (float)c.h;
}

// group-local broadcast: read lane (group_base + idx) of a 16-lane group
#define GSHFL(v, idx) __shfl((v), (lane & 48) + (idx), 64)

// -------------------------------------------------------------------------
// conv-chunk body: MFMA conv1 + maxpool + windowed row sums for one chunk
// of 4 pooled rows. Called twice per block (software-pipelined staging).
// Contains one internal __syncthreads (rowR/edge publish -> final gather).
// -------------------------------------------------------------------------
__device__ __forceinline__ void conv_chunk(
    const unsigned char* xs, const h8v* a, f4v binit,
    int wid, int lane, int n, int g, int tid, int chunk,
    float (*rowR)[C1][4], float (*edgeLo)[C1][4], float (*edgeHi)[C1][4],
    float* __restrict__ partial_slot)
{
    float colsum[4][4];
    #pragma unroll
    for (int py = 0; py < 4; ++py)
        #pragma unroll
        for (int e = 0; e < 4; ++e) colsum[py][e] = 0.0f;

    #pragma unroll
    for (int si = 0; si < 2; ++si) {
        const int s = wid * 2 + si;         // strip: conv cols s*16 .. s*16+15
        const unsigned sByte = (unsigned)(s * 128 + n * 8 + g * 16);

        f4v acc[8];
        #pragma unroll
        for (int q = 0; q < 8; ++q) acc[q] = binit;

        #pragma unroll
        for (int r = 0; r < 12; ++r) {
            h8v bf;
            const unsigned char* bp = xs + r * ROWB + sByte;
            ((ull*)&bf)[0] = *(const ull*)bp;
            ((ull*)&bf)[1] = *(const ull*)(bp + 8);
            #pragma unroll
            for (int ky = 0; ky < 5; ++ky) {
                const int q = r - ky;
                if (q >= 0 && q < 8)
                    acc[q] = __builtin_amdgcn_mfma_f32_16x16x32_f16(
                        a[ky], bf, acc[q], 0, 0, 0);
            }
        }

        // maxpool 2x2 + edge capture + col accumulation
        #pragma unroll
        for (int py = 0; py < 4; ++py) {
            #pragma unroll
            for (int e = 0; e < 4; ++e) {
                float t = fmaxf(acc[2 * py][e], acc[2 * py + 1][e]);
                t = fmaxf(t, __shfl_xor(t, 1, 64));   // pair lanes = pooled col
                if (s == 13 && n >= 12) t = 0.0f;     // junk cols 110,111
                colsum[py][e] += t;
                const int oc = g * 4 + e;
                if (s == 0) {                          // pooled cols 0..3
                    const float c0 = GSHFL(t, 0), c1 = GSHFL(t, 2);
                    const float c2 = GSHFL(t, 4), c3 = GSHFL(t, 6);
                    const float S1 = c0, S2 = S1 + c1, S3 = S2 + c2, S4 = S3 + c3;
                    const float sv = (n == 0) ? S1 : (n == 1) ? S2 : (n == 2) ? S3 : S4;
                    if (n < 4 && oc < C1) edgeLo[py][oc][n] = sv;
                }
                if (s == 13) {                         // pooled cols 106..109
                    const float d109 = GSHFL(t, 10), d108 = GSHFL(t, 8);
                    const float d107 = GSHFL(t, 6),  d106 = GSHFL(t, 4);
                    const float U1 = d109, U2 = U1 + d108, U3 = U2 + d107, U4 = U3 + d106;
                    const float uv = (n == 0) ? U1 : (n == 1) ? U2 : (n == 2) ? U3 : U4;
                    if (n < 4 && oc < C1) edgeHi[py][oc][n] = uv;
                }
            }
        }
    }

    // per-wave row sums: reduce 8 same-parity lanes (each pooled col once)
    #pragma unroll
    for (int py = 0; py < 4; ++py) {
        #pragma unroll
        for (int e = 0; e < 4; ++e) {
            float v = colsum[py][e];
            v += __shfl_xor(v, 2, 64);
            v += __shfl_xor(v, 4, 64);
            v += __shfl_xor(v, 8, 64);
            const int oc = g * 4 + e;
            if (n == 0 && oc < C1) rowR[wid][oc][py] = v;
        }
    }
    __syncthreads();

    // final: slot(oc,ky,kx) = sum_py valid(py,ky) * (rowsum - S_kx - U_{4-kx})
    if (tid < 150) {
        const int oc = tid / 25;
        const int rem = tid - oc * 25;
        const int ky = rem / 5, kx = rem - ky * 5;
        float total = 0.0f;
        #pragma unroll
        for (int py = 0; py < 4; ++py) {
            const int y = chunk * 4 + py;
            const bool valid = (y < P1) && ((unsigned)(y - ky) <= 105u);
            float v = rowR[0][oc][py] + rowR[1][oc][py] + rowR[2][oc][py]
                    + rowR[3][oc][py] + rowR[4][oc][py] + rowR[5][oc][py]
                    + rowR[6][oc][py];
            if (kx > 0) v -= edgeLo[py][oc][kx - 1];
            if (kx < 4) v -= edgeHi[py][oc][3 - kx];
            total += valid ? v : 0.0f;
        }
        partial_slot[tid] = total;
    }
}

// -------------------------------------------------------------------------
// K1 (MFMA f16, software-pipelined): each block runs TWO chunks; chunk-1's
// global loads are issued into registers BEFORE chunk-0's compute, so HBM
// latency hides under MFMA (T14 async-stage split). Grid 896 blocks =
// fully co-resident (<=4 blocks/CU) -> single dispatch round.
// XCD image-affinity: b = (l&7) + 8*((l>>3)&7) puts image b on XCD b%8 —
// the SAME map k3 uses, so k1's x4h writes are k3's same-L2 reads.
// -------------------------------------------------------------------------
__global__ __launch_bounds__(TPB1) void k1_fused(
    const float* __restrict__ x,      // (B,3,224,224)
    const float* __restrict__ w1,     // (6,3,5,5)
    const float* __restrict__ b1,     // (6,)
    float* __restrict__ partial,      // (B,28,PSTRIDE)
    u16* __restrict__ x4h,            // (B,224,224,4) f16 out
    int do_pack)
{
    __shared__ __attribute__((aligned(16))) unsigned char xs[12 * ROWB + 128];
    __shared__ __attribute__((aligned(16))) _Float16 sa[5][64][8];  // A-frags
    __shared__ float rowR[7][C1][4];
    __shared__ float edgeLo[4][C1][4];
    __shared__ float edgeHi[4][C1][4];

    const int l    = blockIdx.x;                 // 0..895
    const int b    = (l & 7) + 8 * ((l >> 3) & 7);
    const int cp   = l >> 6;                     // chunk pair 0..13
    const int chunk0 = 2 * cp, chunk1 = 2 * cp + 1;
    const int gy00 = chunk0 * 8, gy01 = chunk1 * 8;
    const int tid  = threadIdx.x;
    const int wid  = tid >> 6;
    const int lane = tid & 63;
    const int n    = lane & 15;
    const int g    = lane >> 4;

    const float* xb = x + (size_t)b * (Cn * PLANE);
    u16* ob = x4h + (size_t)b * PLANE * 4;

    if (wid == 0) {
        // wave 0: build A-frags (weights, k = ic + 4*kx) into LDS
        #pragma unroll
        for (int ky = 0; ky < 5; ++ky) {
            #pragma unroll
            for (int j = 0; j < 8; ++j) {
                const int kmem = g * 8 + j;
                const int ic = kmem & 3, kx = kmem >> 2;
                float w = 0.0f;
                if (n < C1 && ic < 3 && kx < 5)
                    w = w1[((n * 3 + ic) * 5 + ky) * 5 + kx];
                sa[ky][lane][j] = (_Float16)w;
            }
        }
    } else {
        // waves 1-6: stage chunk0 fp32 NCHW -> f16 NHWC4 LDS (+ x4h pack)
        for (int i = tid - 64; i < 12 * 112; i += TPB1 - 64) {
            const int r = i / 112;
            const int p = i - r * 112;
            const int gy = gy00 + r;
            uint4 U; U.x = U.y = U.z = U.w = 0u;
            if (gy < IMG) {
                const float2 v0 = *(const float2*)(xb + 0 * PLANE + gy * IMG + 2 * p);
                const float2 v1 = *(const float2*)(xb + 1 * PLANE + gy * IMG + 2 * p);
                const float2 v2 = *(const float2*)(xb + 2 * PLANE + gy * IMG + 2 * p);
                U.x = hpack(v0.x, v1.x);
                U.y = hpack(v2.x, 0.0f);
                U.z = hpack(v0.y, v1.y);
                U.w = hpack(v2.y, 0.0f);
            }
            *(uint4*)(xs + r * ROWB + p * 16) = U;
            if (do_pack && r < 8)
                *(uint4*)(ob + ((size_t)gy * IMG + 2 * p) * 4) = U;
        }
    }
    __syncthreads();   // b1

    // per-lane A-frags (one b128 each) + bias init
    h8v a[5];
    #pragma unroll
    for (int ky = 0; ky < 5; ++ky) a[ky] = *(const h8v*)&sa[ky][lane][0];
    f4v binit;
    #pragma unroll
    for (int e = 0; e < 4; ++e) {
        const int oc = g * 4 + e;
        binit[e] = (oc < C1) ? b1[oc] : 0.0f;
    }

    // issue chunk1 loads NOW -> registers (HBM latency hides under chunk0)
    float2 rv0[3], rv1[3], rv2[3];
    #pragma unroll
    for (int k = 0; k < 3; ++k) {
        const int i = tid + k * TPB1;        // 448*3 = 1344 items exactly
        const int r = i / 112, p = i - r * 112;
        const int gy = gy01 + r;
        float2 z; z.x = 0.0f; z.y = 0.0f;
        rv0[k] = z; rv1[k] = z; rv2[k] = z;
        if (gy < IMG) {
            rv0[k] = *(const float2*)(xb + 0 * PLANE + gy * IMG + 2 * p);
            rv1[k] = *(const float2*)(xb + 1 * PLANE + gy * IMG + 2 * p);
            rv2[k] = *(const float2*)(xb + 2 * PLANE + gy * IMG + 2 * p);
        }
    }

    // ---- chunk 0 ----
    conv_chunk(xs, a, binit, wid, lane, n, g, tid, chunk0,
               rowR, edgeLo, edgeHi,
               partial + ((size_t)b * NCHUNK + chunk0) * PSTRIDE);
    __syncthreads();   // b3: final150(c0) done; xs reads done

    // write-back chunk1 regs -> LDS (+ pack)
    #pragma unroll
    for (int k = 0; k < 3; ++k) {
        const int i = tid + k * TPB1;
        const int r = i / 112, p = i - r * 112;
        uint4 U;
        U.x = hpack(rv0[k].x, rv1[k].x);
        U.y = hpack(rv2[k].x, 0.0f);
        U.z = hpack(rv0[k].y, rv1[k].y);
        U.w = hpack(rv2[k].y, 0.0f);
        *(uint4*)(xs + r * ROWB + p * 16) = U;
        const int gy = gy01 + r;
        if (do_pack && r < 8 && gy < IMG)
            *(uint4*)(ob + ((size_t)gy * IMG + 2 * p) * 4) = U;
    }
    __syncthreads();   // b4

    // ---- chunk 1 ----
    conv_chunk(xs, a, binit, wid, lane, n, g, tid, chunk1,
               rowR, edgeLo, edgeHi,
               partial + ((size_t)b * NCHUNK + chunk1) * PSTRIDE);
}

// -------------------------------------------------------------------------
// K2: reduce partials -> wsum_b; feat = b2 + (W2 . wsum_b)/11236 ;
// fc1+relu ; fc2+sigmoid*5. One block (256 threads) per batch element.
// (Separate kernel: round-2's per-k3-block inlined head cost ~+9us total.)
// -------------------------------------------------------------------------
__global__ __launch_bounds__(256) void k2_head(
    const float* __restrict__ partial, const float* __restrict__ w2,
    const float* __restrict__ b2, const float* __restrict__ fc1w,
    const float* __restrict__ fc1b, const float* __restrict__ fc2w,
    const float* __restrict__ fc2b, float* __restrict__ wt_ws,
    float* __restrict__ out)
{
    const int b = blockIdx.x;
    const int tid = threadIdx.x;
    __shared__ float wsb[150];
    __shared__ float sfeat[16];
    __shared__ float sh[8];

    if (tid < 150) {
        const float* p = partial + (size_t)b * NCHUNK * PSTRIDE + tid;
        float s = 0.0f;
        #pragma unroll
        for (int c = 0; c < NCHUNK; ++c) s += p[c * PSTRIDE];
        wsb[tid] = s;
    }
    __syncthreads();
    if (tid < 16) {
        float s = 0.0f;
        for (int j = 0; j < 150; ++j) s += w2[tid * 150 + j] * wsb[j];
        sfeat[tid] = b2[tid] + s * (1.0f / (float)NVALID);
    }
    __syncthreads();
    if (tid < 8) {
        float s = fc1b[tid];
        #pragma unroll
        for (int j = 0; j < 16; ++j) s += fc1w[tid * 16 + j] * sfeat[j];
        sh[tid] = fmaxf(s, 0.0f);
    }
    __syncthreads();
    if (tid < 2) {
        float s = fc2b[tid];
        #pragma unroll
        for (int j = 0; j < 8; ++j) s += fc2w[tid * 8 + j] * sh[j];
        float sig = (s >= 0.0f) ? (1.0f / (1.0f + expf(-s)))
                                : (expf(s) / (1.0f + expf(s)));
        const float wgt = 5.0f * sig;
        wt_ws[b * 2 + tid] = wgt;
        out[POOLED_SIZE + b * 2 + tid] = wgt;
    }
}

// -------------------------------------------------------------------------
// Clamp-coordinate sampling (equivalent to corner-clamp border mode).
// -------------------------------------------------------------------------
__device__ __forceinline__ void sample_coords(
    float gxn, float gyn, int& x0, int& y0, float& wx, float& wy)
{
    float ix = ((gxn + 1.0f) * (float)IMG - 1.0f) * 0.5f;
    float iy = ((gyn + 1.0f) * (float)IMG - 1.0f) * 0.5f;
    ix = fminf(fmaxf(ix, 0.0f), (float)(IMG - 1));
    iy = fminf(fmaxf(iy, 0.0f), (float)(IMG - 1));
    x0 = (int)ix; if (x0 > IMG - 2) x0 = IMG - 2;
    y0 = (int)iy; if (y0 > IMG - 2) y0 = IMG - 2;
    wx = ix - (float)x0;
    wy = iy - (float)y0;
}

// -------------------------------------------------------------------------
// K3 (f16 NHWC4): log-polar grid sample + 10x10 avg pool.
// Merged taps: px (x0,x0+1) contiguous 16B -> one uint4 per row per tap.
// XCD-affinity swizzle: b = (L&7) + 8*(q>>5), 8 images/XCD; matches k1's
// write affinity so x4h gathers hit the local L2.
// -------------------------------------------------------------------------
__global__ __launch_bounds__(640) void k3_sample_pool_f16(
    const u16* __restrict__ x4h,      // (B,224,224,4) f16
    const float* __restrict__ ltp,
    const float* __restrict__ wt,
    float* __restrict__ out)
{
    __shared__ float part[3 * Wg];

    const int L = blockIdx.x;         // 0..2047
    const int q = L >> 3;             // 0..255
    const int h = q & 31;
    const int b = (L & 7) + 8 * (q >> 5);
    const int tid = threadIdx.x;

    const float w0 = wt[b * 2 + 0];
    const float w1 = wt[b * 2 + 1];
    const float l0 = ltp[b * 2 + 0];
    const float l1 = ltp[b * 2 + 1];
    const float start = logf(0.01f * w0);
    const float stop  = logf(0.6f  * w1);
    const float dr = stop - start;

    const float angle = 6.283185307179586f * (float)tid / (float)Wg;
    const float sn = __sinf(angle);
    const float cs = __cosf(angle);

    const u16* xb4 = x4h + (size_t)b * PLANE * 4;

    const float ratio = expf(dr * (1.0f / (float)(Hg - 1)));
    float r = expf(start + dr * ((float)(h * UPR) / (float)(Hg - 1)));

    float acc0 = 0.0f, acc1 = 0.0f, acc2 = 0.0f;
    #pragma unroll
    for (int i = 0; i < UPR; ++i) {
        int x0, y0; float wx, wy;
        sample_coords(r * sn + l0, r * cs + l1, x0, y0, wx, wy);
        r *= ratio;

        const u16* base = xb4 + ((size_t)(y0 * IMG + x0)) * 4;
        const uint4 R0 = *(const uint4*)(base);            // px x0|x0+1, row y0
        const uint4 R1 = *(const uint4*)(base + IMG * 4);  // row y0+1

        const float wx0 = 1.0f - wx, wy0 = 1.0f - wy;
        const float w00 = wx0 * wy0, w01 = wx * wy0;
        const float w10 = wx0 * wy,  w11 = wx * wy;

        acc0 += w00*h2lo(R0.x) + w01*h2lo(R0.z) + w10*h2lo(R1.x) + w11*h2lo(R1.z);
        acc1 += w00*h2hi(R0.x) + w01*h2hi(R0.z) + w10*h2hi(R1.x) + w11*h2hi(R1.z);
        acc2 += w00*h2lo(R0.y) + w01*h2lo(R0.w) + w10*h2lo(R1.y) + w11*h2lo(R1.w);
    }
    part[0 * Wg + tid] = acc0;
    part[1 * Wg + tid] = acc1;
    part[2 * Wg + tid] = acc2;
    __syncthreads();

    if (tid < Cn * Ww) {
        const int c = tid / Ww;
        const int w = tid % Ww;
        const float* p = part + c * Wg + w * UPT;
        float s = 0.0f;
        #pragma unroll
        for (int j = 0; j < UPT; ++j) s += p[j];
        out[(((size_t)b * Cn + c) * Hh + h) * Ww + w] = s * (1.0f / (UPR * UPT));
    }
}

// -------------------------------------------------------------------------
// K3 fallback (NCHW fp32 scalar gathers) — only if ws too small for x4h.
// -------------------------------------------------------------------------
__global__ __launch_bounds__(640) void k3_sample_pool_nchw(
    const float* __restrict__ x, const float* __restrict__ ltp,
    const float* __restrict__ wt, float* __restrict__ out)
{
    __shared__ float part[3 * Wg];
    const int L = blockIdx.x;
    const int q = L >> 3;
    const int h = q & 31;
    const int b = (L & 7) + 8 * (q >> 5);
    const int tid = threadIdx.x;

    const float w0 = wt[b * 2 + 0];
    const float w1 = wt[b * 2 + 1];
    const float l0 = ltp[b * 2 + 0];
    const float l1 = ltp[b * 2 + 1];
    const float start = logf(0.01f * w0);
    const float stop  = logf(0.6f  * w1);
    const float dr = stop - start;
    const float angle = 6.283185307179586f * (float)tid / (float)Wg;
    const float sn = __sinf(angle);
    const float cs = __cosf(angle);
    const float* xb = x + (size_t)b * Cn * PLANE;

    const float ratio = expf(dr * (1.0f / (float)(Hg - 1)));
    float r = expf(start + dr * ((float)(h * UPR) / (float)(Hg - 1)));

    float acc0 = 0.0f, acc1 = 0.0f, acc2 = 0.0f;
    #pragma unroll
    for (int i = 0; i < UPR; ++i) {
        int x0, y0; float wx, wy;
        sample_coords(r * sn + l0, r * cs + l1, x0, y0, wx, wy);
        r *= ratio;
        const float wx0 = 1.0f - wx, wy0 = 1.0f - wy;
        const float w00 = wx0 * wy0, w01 = wx * wy0;
        const float w10 = wx0 * wy,  w11 = wx * wy;
        const int o00 = y0 * IMG + x0;
        acc0 += w00*xb[o00] + w01*xb[o00+1] + w10*xb[o00+IMG] + w11*xb[o00+IMG+1];
        const float* x1p = xb + PLANE;
        acc1 += w00*x1p[o00] + w01*x1p[o00+1] + w10*x1p[o00+IMG] + w11*x1p[o00+IMG+1];
        const float* x2p = xb + 2 * PLANE;
        acc2 += w00*x2p[o00] + w01*x2p[o00+1] + w10*x2p[o00+IMG] + w11*x2p[o00+IMG+1];
    }
    part[0 * Wg + tid] = acc0;
    part[1 * Wg + tid] = acc1;
    part[2 * Wg + tid] = acc2;
    __syncthreads();

    if (tid < Cn * Ww) {
        const int c = tid / Ww;
        const int w = tid % Ww;
        const float* p = part + c * Wg + w * UPT;
        float s = 0.0f;
        #pragma unroll
        for (int j = 0; j < UPT; ++j) s += p[j];
        out[(((size_t)b * Cn + c) * Hh + h) * Ww + w] = s * (1.0f / (UPR * UPT));
    }
}

// -------------------------------------------------------------------------
extern "C" void kernel_launch(void* const* d_in, const int* in_sizes, int n_in,
                              void* d_out, int out_size, void* d_ws, size_t ws_size,
                              hipStream_t stream) {
    const float* x       = (const float*)d_in[0];
    const float* ltp     = (const float*)d_in[1];
    const float* conv1_w = (const float*)d_in[2];
    const float* conv1_b = (const float*)d_in[3];
    const float* conv2_w = (const float*)d_in[4];
    const float* conv2_b = (const float*)d_in[5];
    const float* fc1_w   = (const float*)d_in[6];
    const float* fc1_b   = (const float*)d_in[7];
    const float* fc2_w   = (const float*)d_in[8];
    const float* fc2_b   = (const float*)d_in[9];
    float* out = (float*)d_out;

    const int do_pack = (ws_size >= WS_NEEDED) ? 1 : 0;

    float* part_ws = (float*)d_ws;                // B*28*PSTRIDE
    float* wt_ws   = part_ws + PART_FLOATS;       // B*2
    u16*   x4h     = (u16*)(wt_ws + Bn * 2);      // 8B-aligned

    k1_fused<<<dim3(Bn * NCHUNK / 2), dim3(TPB1), 0, stream>>>(
        x, conv1_w, conv1_b, part_ws, x4h, do_pack);
    k2_head<<<dim3(Bn), dim3(256), 0, stream>>>(part_ws, conv2_w, conv2_b,
                                                fc1_w, fc1_b, fc2_w, fc2_b,
                                                wt_ws, out);
    if (do_pack)
        k3_sample_pool_f16<<<dim3(Hh * Bn), dim3(Wg), 0, stream>>>(x4h, ltp, wt_ws, out);
    else
        k3_sample_pool_nchw<<<dim3(Hh * Bn), dim3(Wg), 0, stream>>>(x, ltp, wt_ws, out);
}